// Round 5
// baseline (71.698 us; speedup 1.0000x reference)
//
#include <hip/hip_runtime.h>

#define NUM_CLASSES 80

typedef float f32x4 __attribute__((ext_vector_type(4)));

__global__ __launch_bounds__(256) void targets_kernel(
    const float* __restrict__ ann, const float* __restrict__ anchors,
    float* __restrict__ cls, float* __restrict__ reg, float* __restrict__ states,
    int A, int N) {
#pragma clang fp contract(off)
  __shared__ float4 sbox[64];
  __shared__ float sarea[64];
  __shared__ int slabel[64];

  const int b = blockIdx.y;
  const int a0 = blockIdx.x * 256;
  const int tid = threadIdx.x;

  // Stage this batch's 64 GT boxes into LDS (x1,y1,x2,y2), area, label.
  if (tid < N) {
    const float* p = ann + ((size_t)b * N + tid) * 5;
    float x1 = p[0], y1 = p[1], x2 = p[2], y2 = p[3];
    sbox[tid] = make_float4(x1, y1, x2, y2);
    sarea[tid] = (x2 - x1) * (y2 - y1);
    slabel[tid] = (int)p[4];
  }
  __syncthreads();

  // Phase 0: stream this tile's cls ZEROS immediately with NON-TEMPORAL
  // stores (write-once output; bypass L2 retention). Compute overlaps drain.
  const int nvalid = min(256, A - a0);
  f32x4* clsv = reinterpret_cast<f32x4*>(cls + ((size_t)b * A + a0) * NUM_CLASSES);
  const int total = nvalid * (NUM_CLASSES / 4);
  const f32x4 z = {0.0f, 0.0f, 0.0f, 0.0f};
  for (int it = tid; it < total; it += 256) {
    __builtin_nontemporal_store(z, &clsv[it]);
  }

  const int a = a0 + tid;
  const bool valid = (a < A);
  const int aidx = valid ? a : 0;
  const float4 anc = reinterpret_cast<const float4*>(anchors)[aidx];
  const float area_a = (anc.z - anc.x) * (anc.w - anc.y);

  // Division-free IoU argmax: keep (best_inter, best_uni); update iff
  // inter_j * best_uni > best_inter * uni_j (all > 0, first-max-wins).
  float best_inter, best_uni;
  {
    float4 bx = sbox[0];
    float iw = fminf(anc.z, bx.z) - fmaxf(anc.x, bx.x);
    float ih = fminf(anc.w, bx.w) - fmaxf(anc.y, bx.y);
    best_inter = fmaxf(iw, 0.0f) * fmaxf(ih, 0.0f);
    best_uni = fmaxf(area_a + sarea[0] - best_inter, 1e-8f);
  }
  int bestj = 0;
  #pragma unroll 8
  for (int j = 1; j < N; ++j) {
    float4 bx = sbox[j];
    float iw = fminf(anc.z, bx.z) - fmaxf(anc.x, bx.x);
    float ih = fminf(anc.w, bx.w) - fmaxf(anc.y, bx.y);
    float inter = fmaxf(iw, 0.0f) * fmaxf(ih, 0.0f);
    float uni = fmaxf(area_a + sarea[j] - inter, 1e-8f);
    bool upd = (inter * best_uni) > (best_inter * uni);
    best_inter = upd ? inter : best_inter;
    best_uni = upd ? uni : best_uni;
    bestj = upd ? j : bestj;
  }
  const float best = best_inter / best_uni;

  const bool positive = best >= 0.5f;
  const bool ignore = (best > 0.4f) && !positive;
  const float state = positive ? 1.0f : (ignore ? -1.0f : 0.0f);

  int lab = 0;
  if (valid) {
    float4 bt = sbox[bestj];
    float aw = anc.z - anc.x;
    float ah = anc.w - anc.y;
    f32x4 r;
    r.x = ((bt.x - anc.x) / aw) / 0.2f;
    r.y = ((bt.y - anc.y) / ah) / 0.2f;
    r.z = ((bt.z - anc.z) / aw) / 0.2f;
    r.w = ((bt.w - anc.w) / ah) / 0.2f;
    __builtin_nontemporal_store(r, &reinterpret_cast<f32x4*>(reg)[(size_t)b * A + a]);
    __builtin_nontemporal_store(state, &states[(size_t)b * A + a]);
    lab = slabel[bestj];
  }

  // Order the sparse 1.0 rewrite after the zero stream (WAW across waves).
  asm volatile("s_waitcnt vmcnt(0)" ::: "memory");
  __syncthreads();

  if (valid && positive) {
    cls[((size_t)b * A + a) * NUM_CLASSES + lab] = 1.0f;
  }
}

extern "C" void kernel_launch(void* const* d_in, const int* in_sizes, int n_in,
                              void* d_out, int out_size, void* d_ws, size_t ws_size,
                              hipStream_t stream) {
  const float* ann = (const float*)d_in[0];
  const float* anchors = (const float*)d_in[1];

  const int A = in_sizes[1] / 4;                                   // 120000
  const int B = (int)((long long)out_size / ((long long)A * (NUM_CLASSES + 5)));  // 8
  const int N = in_sizes[0] / (B * 5);                             // 64

  float* out = (float*)d_out;
  float* cls = out;
  float* reg = cls + (size_t)B * A * NUM_CLASSES;
  float* states = reg + (size_t)B * A * 4;

  dim3 grid((A + 255) / 256, B);
  targets_kernel<<<grid, 256, 0, stream>>>(ann, anchors, cls, reg, states, A, N);
}

// Round 6
// 65.928 us; speedup vs baseline: 1.0875x; 1.0875x over previous
//
#include <hip/hip_runtime.h>

#define NUM_CLASSES 80
#define NBLK 1024

__global__ __launch_bounds__(256) void targets_kernel(
    const float* __restrict__ ann, const float* __restrict__ anchors,
    float* __restrict__ cls, float* __restrict__ reg, float* __restrict__ states,
    int A, int N, int B, int ntiles) {
#pragma clang fp contract(off)
  __shared__ float4 sbox[512];
  __shared__ float sarea[512];
  __shared__ int slabel[512];
  __shared__ int sinfo[256];

  const int tid = threadIdx.x;
  const int NB = N * B;  // 512 boxes total across all batches

  // Preload ALL batches' GT boxes into LDS once (13 KB).
  for (int i = tid; i < NB; i += 256) {
    const float* p = ann + (size_t)i * 5;
    float x1 = p[0], y1 = p[1], x2 = p[2], y2 = p[3];
    sbox[i] = make_float4(x1, y1, x2, y2);
    sarea[i] = (x2 - x1) * (y2 - y1);
    slabel[i] = (int)p[4];
  }
  __syncthreads();

  // Persistent grid-stride over all (batch, tile) pairs. A wave issues tile
  // t's stores then immediately computes tile t+1 — stores drain in the
  // background, keeping the write pipe full instead of per-block pulses.
  const int T = B * ntiles;
  for (int t = blockIdx.x; t < T; t += NBLK) {
    const int b = t / ntiles;
    const int tile = t - b * ntiles;
    const int a0 = tile * 256;
    const int a = a0 + tid;
    const bool valid = (a < A);
    const int aidx = valid ? a : 0;
    const float4 anc = reinterpret_cast<const float4*>(anchors)[aidx];
    const float area_a = (anc.z - anc.x) * (anc.w - anc.y);
    const int boff = b * N;

    // Division-free IoU argmax (first-max-wins via strict >).
    float best_inter, best_uni;
    {
      float4 bx = sbox[boff];
      float iw = fminf(anc.z, bx.z) - fmaxf(anc.x, bx.x);
      float ih = fminf(anc.w, bx.w) - fmaxf(anc.y, bx.y);
      best_inter = fmaxf(iw, 0.0f) * fmaxf(ih, 0.0f);
      best_uni = fmaxf(area_a + sarea[boff] - best_inter, 1e-8f);
    }
    int bestj = 0;
    #pragma unroll 8
    for (int j = 1; j < N; ++j) {
      float4 bx = sbox[boff + j];
      float iw = fminf(anc.z, bx.z) - fmaxf(anc.x, bx.x);
      float ih = fminf(anc.w, bx.w) - fmaxf(anc.y, bx.y);
      float inter = fmaxf(iw, 0.0f) * fmaxf(ih, 0.0f);
      float uni = fmaxf(area_a + sarea[boff + j] - inter, 1e-8f);
      bool upd = (inter * best_uni) > (best_inter * uni);
      best_inter = upd ? inter : best_inter;
      best_uni = upd ? uni : best_uni;
      bestj = upd ? j : bestj;
    }
    const float best = best_inter / best_uni;

    const bool positive = best >= 0.5f;
    const bool ignore = (best > 0.4f) && !positive;
    const float state = positive ? 1.0f : (ignore ? -1.0f : 0.0f);

    if (valid) {
      float4 bt = sbox[boff + bestj];
      float aw = anc.z - anc.x;
      float ah = anc.w - anc.y;
      float4 r;
      r.x = ((bt.x - anc.x) / aw) / 0.2f;
      r.y = ((bt.y - anc.y) / ah) / 0.2f;
      r.z = ((bt.z - anc.z) / aw) / 0.2f;
      r.w = ((bt.w - anc.w) / ah) / 0.2f;
      reinterpret_cast<float4*>(reg)[(size_t)b * A + a] = r;
      states[(size_t)b * A + a] = state;
    }

    // Protect sinfo against previous tile's phase-2 readers (WAR), then
    // publish. Neither barrier waits on store completion (vmem is free-running).
    __syncthreads();
    sinfo[tid] = positive ? slabel[boff + bestj] : -1;
    const int npos = __syncthreads_count(valid && positive);

    // Coalesced one-hot cls writes for this tile.
    const int nvalid = min(256, A - a0);
    float4* clsv = reinterpret_cast<float4*>(cls + ((size_t)b * A + a0) * NUM_CLASSES);
    const int total = nvalid * (NUM_CLASSES / 4);
    if (npos == 0) {
      const float4 z = make_float4(0.0f, 0.0f, 0.0f, 0.0f);
      for (int it = tid; it < total; it += 256) clsv[it] = z;
    } else {
      for (int it = tid; it < total; it += 256) {
        int al = it / (NUM_CLASSES / 4);
        int w = it - al * (NUM_CLASSES / 4);
        int lab = sinfo[al];  // -1 if not positive
        int c0 = w * 4;
        float4 v;
        v.x = (lab == c0 + 0) ? 1.0f : 0.0f;
        v.y = (lab == c0 + 1) ? 1.0f : 0.0f;
        v.z = (lab == c0 + 2) ? 1.0f : 0.0f;
        v.w = (lab == c0 + 3) ? 1.0f : 0.0f;
        clsv[it] = v;
      }
    }
  }
}

extern "C" void kernel_launch(void* const* d_in, const int* in_sizes, int n_in,
                              void* d_out, int out_size, void* d_ws, size_t ws_size,
                              hipStream_t stream) {
  const float* ann = (const float*)d_in[0];
  const float* anchors = (const float*)d_in[1];

  const int A = in_sizes[1] / 4;                                   // 120000
  const int B = (int)((long long)out_size / ((long long)A * (NUM_CLASSES + 5)));  // 8
  const int N = in_sizes[0] / (B * 5);                             // 64
  const int ntiles = (A + 255) / 256;                              // 469

  float* out = (float*)d_out;
  float* cls = out;
  float* reg = cls + (size_t)B * A * NUM_CLASSES;
  float* states = reg + (size_t)B * A * 4;

  targets_kernel<<<NBLK, 256, 0, stream>>>(ann, anchors, cls, reg, states, A, N, B, ntiles);
}